// Round 9
// baseline (167.186 us; speedup 1.0000x reference)
//
#include <hip/hip_runtime.h>
#include <math.h>

#define BATCH 64
#define HH 512
#define WW 512
#define KRAD 15
#define KSZ 31
#define NTOT ((size_t)BATCH * HH * WW)
#define TILE_Y 64
#define NCHUNK (HH / TILE_Y)            // 8
#define NBLK (BATCH * NCHUNK)           // 512 blocks
#define RING 64                         // fp16 ring rows (mod-64 free)
#define NSTEP 4                         // 4 steps x 16 output rows
#define STEP_R 16

typedef _Float16 h8 __attribute__((ext_vector_type(8)));

// ---------------------------------------------------------------------------
// Ring-buffer H-strip + producer/consumer wave split.
// TILE_Y=64 (halo redundancy 1.47x) with only a 64-row fp16 ring in LDS
// (64 KB -> 2 blocks/CU = 32 waves/CU). Per 16-row step: waves 8..15 scan
// the next 16 H rows (wave shuffle-scan, zero-written when out of range)
// while waves 0..7 (one column each) run the vertical sliding 31-window +
// loss math. One barrier per step. Ring aliasing verified: step-k writes
// (rel 16k+46..61 -> slots 16k-18..-3 mod 64) are disjoint from step-k
// reads (rel 16k-1..16k+45).
// ---------------------------------------------------------------------------
__global__ __launch_bounds__(1024, 8) void mega_kernel(const float* __restrict__ logits,
                                                       const float* __restrict__ targ,
                                                       float* __restrict__ pbuf) {
    __shared__ _Float16 Hring[RING * WW];   // 64 KB
    __shared__ float red[3][16];

    const int b     = blockIdx.x >> 3;          // batch
    const int chunk = blockIdx.x & (NCHUNK - 1);
    const int y0    = chunk * TILE_Y;

    const int wave = threadIdx.x >> 6;          // 0..15
    const int lane = threadIdx.x & 63;

    // Scan one H row (rel = y_abs - (y0-15)) into ring slot rel&63.
    // Zero-writes for out-of-range rows (zero-pad semantics, no consumer guards).
    auto scan_row = [&](int rel) {
        const int y_abs = y0 - KRAD + rel;
        h8 hv = {};
        if (y_abs >= 0 && y_abs < HH) {
            const float4* rp = (const float4*)(targ + ((size_t)b * HH + y_abs) * WW);
            float4 a  = rp[2 * lane];
            float4 b4 = rp[2 * lane + 1];
            float v[8] = {a.x, a.y, a.z, a.w, b4.x, b4.y, b4.z, b4.w};

            float T = 0.0f;
            float P[8];
#pragma unroll
            for (int j = 0; j < 8; ++j) { T += v[j]; P[j] = T; }

            float incl = T;
#pragma unroll
            for (int d = 1; d < 64; d <<= 1) {
                float n = __shfl_up(incl, d, 64);
                if (lane >= d) incl += n;
            }
            const float excl = incl - T;
            const float tot  = __shfl(incl, 63, 64);
#pragma unroll
            for (int j = 0; j < 8; ++j) P[j] += excl;

#pragma unroll
            for (int j = 0; j < 8; ++j) {
                const int q   = j + 15;             // 15..22 (compile-time)
                const int seg = lane + (q >> 3);
                float hi_sh = __shfl(P[q & 7], seg > 63 ? 63 : seg, 64);
                float hi    = (seg > 63) ? tot : hi_sh;
                float lo_sh = __shfl(P[j], lane >= 2 ? lane - 2 : 0, 64);
                float lo    = (lane >= 2) ? lo_sh : 0.0f;
                hv[j] = (_Float16)(hi - lo);
            }
        }
        *(h8*)&Hring[(rel & (RING - 1)) * WW + lane * 8] = hv;
    };

    // ---- Warmup: H rows rel 0..45 (all 16 waves; wave-uniform guards) ----
#pragma unroll
    for (int i = 0; i < 3; ++i) {
        const int rel = wave + 16 * i;
        if (rel <= 45) scan_row(rel);
    }
    __syncthreads();

    // ---- Steps: producers (waves 8..15) scan ahead; consumers compute ----
    float a_wbce = 0.0f, a_int = 0.0f, a_tot = 0.0f;

    const int x = threadIdx.x;                  // consumer column (x < 512)
    const float* Tp = targ   + ((size_t)b * HH + y0) * WW + x;
    const float* Lp = logits + ((size_t)b * HH + y0) * WW + x;
    const float inv_ksq = 1.0f / (float)(KSZ * KSZ);

    float vsum = 0.0f;
    if (x < WW) {
        // window at yrel=0: rel 0..30 (invalid rows are zero-filled)
#pragma unroll
        for (int r = 0; r <= 30; ++r) vsum += (float)Hring[r * WW + x];
    }

    for (int k = 0; k < NSTEP; ++k) {
        if (wave >= 8) {
            if (k < NSTEP - 1) {
                const int rel = 16 * k + 46 + (wave - 8) * 2;
                scan_row(rel);
                scan_row(rel + 1);
            }
        } else {
#pragma unroll 4
            for (int j = 0; j < STEP_R; ++j) {
                const int yrel = 16 * k + j;
                if (yrel > 0) {
                    // window [y-15, y+15]: add row y+15 (rel yrel+30),
                    // sub row y-16 (rel yrel-1); both pre-zeroed if invalid.
                    vsum += (float)Hring[((yrel + 30) & (RING - 1)) * WW + x]
                          - (float)Hring[((yrel - 1) & (RING - 1)) * WW + x];
                }

                const float s = vsum * inv_ksq;
                const float t = Tp[(size_t)yrel * WW];
                const float L = __builtin_nontemporal_load(Lp + (size_t)yrel * WW);

                const float weit = 1.0f + 5.0f * fabsf(s - t);
                const float e  = __expf(-fabsf(L));
                const float r  = __builtin_amdgcn_rcpf(1.0f + e);
                const float lg = __logf(1.0f + e);          // softplus(-|L|)
                const float sp  = fmaxf(L, 0.0f) + lg;      // softplus(L)
                const float bce = sp - t * L;
                const float p   = (L >= 0.0f) ? r : e * r;  // sigmoid(L)

                a_wbce += weit * bce;
                a_int  += p * t * weit;
                a_tot  += (p + t) * weit;
            }
        }
        __syncthreads();
    }

    // ---- Block reduction (producers contribute zeros) ----
#pragma unroll
    for (int off = 32; off > 0; off >>= 1) {
        a_wbce += __shfl_down(a_wbce, off, 64);
        a_int  += __shfl_down(a_int,  off, 64);
        a_tot  += __shfl_down(a_tot,  off, 64);
    }

    if (lane == 0) {
        red[0][wave] = a_wbce; red[1][wave] = a_int; red[2][wave] = a_tot;
    }
    __syncthreads();
    if (threadIdx.x == 0) {
        float w = 0.0f, i2 = 0.0f, t2 = 0.0f;
#pragma unroll
        for (int kk = 0; kk < 16; ++kk) { w += red[0][kk]; i2 += red[1][kk]; t2 += red[2][kk]; }
        pbuf[blockIdx.x]            = w;
        pbuf[NBLK + blockIdx.x]     = i2;
        pbuf[2 * NBLK + blockIdx.x] = t2;
    }
}

// ---------------------------------------------------------------------------
// Finalize: reduce 512 partials per quantity (double accum) + scalar.
// ---------------------------------------------------------------------------
__global__ __launch_bounds__(256) void finalize_kernel(const float* __restrict__ pbuf,
                                                       float* __restrict__ out) {
    const int tidx = threadIdx.x;
    double w = 0.0, i2 = 0.0, t2 = 0.0;
    for (int k = tidx; k < NBLK; k += 256) {
        w  += (double)pbuf[k];
        i2 += (double)pbuf[NBLK + k];
        t2 += (double)pbuf[2 * NBLK + k];
    }
#pragma unroll
    for (int off = 32; off > 0; off >>= 1) {
        w  += __shfl_down(w,  off, 64);
        i2 += __shfl_down(i2, off, 64);
        t2 += __shfl_down(t2, off, 64);
    }
    __shared__ double red[3][4];
    const int wave = tidx >> 6;
    if ((tidx & 63) == 0) { red[0][wave] = w; red[1][wave] = i2; red[2][wave] = t2; }
    __syncthreads();
    if (tidx == 0) {
        double ws = 0.0, is = 0.0, ts = 0.0;
        for (int k = 0; k < 4; ++k) { ws += red[0][k]; is += red[1][k]; ts += red[2][k]; }
        const double wbce   = ws / (double)NTOT;
        const double union_ = ts - is;
        const double wiou   = 1.0 - (is + 1.0) / (union_ + 1.0);
        out[0] = (float)(wbce + wiou);
    }
}

extern "C" void kernel_launch(void* const* d_in, const int* in_sizes, int n_in,
                              void* d_out, int out_size, void* d_ws, size_t ws_size,
                              hipStream_t stream) {
    const float* logits = (const float*)d_in[0];
    const float* targ   = (const float*)d_in[1];
    float* out          = (float*)d_out;
    float* pbuf         = (float*)d_ws;     // 3*NBLK floats (6 KB)

    mega_kernel<<<NBLK, 1024, 0, stream>>>(logits, targ, pbuf);
    finalize_kernel<<<1, 256, 0, stream>>>(pbuf, out);
}

// Round 10
// 149.330 us; speedup vs baseline: 1.1196x; 1.1196x over previous
//
#include <hip/hip_runtime.h>
#include <math.h>

#define BATCH 64
#define HH 512
#define WW 512
#define KRAD 15
#define KSZ 31
#define NTOT ((size_t)BATCH * HH * WW)
#define TILE_Y 64
#define NCHUNK (HH / TILE_Y)            // 8
#define NBLK (BATCH * NCHUNK)           // 512 blocks (one co-resident generation)
#define RING 63                         // fp16 ring rows (63 KB -> 2 blocks/CU)
#define HROWS (TILE_Y + 2 * KRAD)       // 94 H rows per tile (1.47x redundancy)

typedef _Float16 h8 __attribute__((ext_vector_type(8)));

// ---------------------------------------------------------------------------
// TILE_Y=64 via a 63-row fp16 ring, two whole-block phases (R6/R7 shape):
//   scan rel 0..61 -> B -> compute rows 0..31 -> B -> scan rel 62..93
//   (slots 62,0..30; live slots 31..61 untouched) -> B -> compute rows 32..63.
// vsum carries across phases in-register (warmup once per 64 rows).
// All 16 waves scan; threads 0..511 compute (1 col each, 64 rows).
// ---------------------------------------------------------------------------
__global__ __launch_bounds__(1024, 8) void mega_kernel(const float* __restrict__ logits,
                                                       const float* __restrict__ targ,
                                                       float* __restrict__ pbuf) {
    __shared__ _Float16 Hring[RING * WW];   // 63 KB
    __shared__ float red[3][16];

    const int b     = blockIdx.x >> 3;          // batch
    const int chunk = blockIdx.x & (NCHUNK - 1);
    const int y0    = chunk * TILE_Y;

    const int wave = threadIdx.x >> 6;          // 0..15
    const int lane = threadIdx.x & 63;

    // Scan one H row (rel = y_abs - (y0-15)) into ring slot rel mod 63.
    // Zero-writes for out-of-range rows (zero-pad semantics).
    auto scan_row = [&](int rel) {
        const int y_abs = y0 - KRAD + rel;
        h8 hv = {};
        if (y_abs >= 0 && y_abs < HH) {
            const float4* rp = (const float4*)(targ + ((size_t)b * HH + y_abs) * WW);
            float4 a  = rp[2 * lane];
            float4 b4 = rp[2 * lane + 1];
            float v[8] = {a.x, a.y, a.z, a.w, b4.x, b4.y, b4.z, b4.w};

            float T = 0.0f;
            float P[8];
#pragma unroll
            for (int j = 0; j < 8; ++j) { T += v[j]; P[j] = T; }

            float incl = T;
#pragma unroll
            for (int d = 1; d < 64; d <<= 1) {
                float n = __shfl_up(incl, d, 64);
                if (lane >= d) incl += n;
            }
            const float excl = incl - T;
            const float tot  = __shfl(incl, 63, 64);
#pragma unroll
            for (int j = 0; j < 8; ++j) P[j] += excl;

#pragma unroll
            for (int j = 0; j < 8; ++j) {
                const int q   = j + 15;             // 15..22 (compile-time)
                const int seg = lane + (q >> 3);
                float hi_sh = __shfl(P[q & 7], seg > 63 ? 63 : seg, 64);
                float hi    = (seg > 63) ? tot : hi_sh;
                float lo_sh = __shfl(P[j], lane >= 2 ? lane - 2 : 0, 64);
                float lo    = (lane >= 2) ? lo_sh : 0.0f;
                hv[j] = (_Float16)(hi - lo);
            }
        }
        const int slot = (rel < RING) ? rel : rel - RING;
        *(h8*)&Hring[slot * WW + lane * 8] = hv;
    };

    // ---- Phase A scan: rel 0..61 (4 rows/wave, wave-uniform guard) ----
#pragma unroll
    for (int i = 0; i < 4; ++i) {
        const int rel = wave + 16 * i;
        if (rel < 62) scan_row(rel);
    }
    __syncthreads();

    // ---- Compute setup (threads 0..511, one column each) ----
    const int x = threadIdx.x;
    const float* Tp = targ   + ((size_t)b * HH + y0) * WW + x;
    const float* Lp = logits + ((size_t)b * HH + y0) * WW + x;
    const float inv_ksq = 1.0f / (float)(KSZ * KSZ);
    float a_wbce = 0.0f, a_int = 0.0f, a_tot = 0.0f;

    float vsum = 0.0f;
    if (x < WW) {
        // window for row 0: rel 0..30 (invalid rows zero-filled)
#pragma unroll
        for (int r = 0; r <= 30; ++r) vsum += (float)Hring[r * WW + x];
    }

    // one 32-row compute phase (vsum carried in-register across phases)
    auto compute32 = [&](int ylo) {
        if (x < WW) {
#pragma unroll 4
            for (int j = 0; j < 32; ++j) {
                const int y = ylo + j;
                if (y > 0) {
                    // window [y-15,y+15]: add rel y+30, sub rel y-1 (slot y-1 <= 62)
                    const int ra = y + 30;
                    const int sa = (ra < RING) ? ra : ra - RING;
                    vsum += (float)Hring[sa * WW + x]
                          - (float)Hring[(y - 1) * WW + x];
                }

                const float s = vsum * inv_ksq;
                const float t = Tp[(size_t)y * WW];
                const float L = __builtin_nontemporal_load(Lp + (size_t)y * WW);

                const float weit = 1.0f + 5.0f * fabsf(s - t);
                const float e  = __expf(-fabsf(L));
                const float r  = __builtin_amdgcn_rcpf(1.0f + e);
                const float lg = __logf(1.0f + e);          // softplus(-|L|)
                const float sp  = fmaxf(L, 0.0f) + lg;      // softplus(L)
                const float bce = sp - t * L;
                const float p   = (L >= 0.0f) ? r : e * r;  // sigmoid(L)

                a_wbce += weit * bce;
                a_int  += p * t * weit;
                a_tot  += (p + t) * weit;
            }
        }
    };

    // ---- Phase A compute: rows 0..31 (reads slots 0..61 only) ----
    compute32(0);
    __syncthreads();

    // ---- Phase B scan: rel 62..93 -> slots 62, 0..30 (2 rows/wave) ----
    scan_row(62 + wave);
    scan_row(78 + wave);
    __syncthreads();

    // ---- Phase B compute: rows 32..63 (subs rel 31..62 live; adds rel 62..93) ----
    compute32(32);

    // ---- Block reduction ----
#pragma unroll
    for (int off = 32; off > 0; off >>= 1) {
        a_wbce += __shfl_down(a_wbce, off, 64);
        a_int  += __shfl_down(a_int,  off, 64);
        a_tot  += __shfl_down(a_tot,  off, 64);
    }

    if (lane == 0) {
        red[0][wave] = a_wbce; red[1][wave] = a_int; red[2][wave] = a_tot;
    }
    __syncthreads();
    if (threadIdx.x == 0) {
        float w = 0.0f, i2 = 0.0f, t2 = 0.0f;
#pragma unroll
        for (int k = 0; k < 16; ++k) { w += red[0][k]; i2 += red[1][k]; t2 += red[2][k]; }
        pbuf[blockIdx.x]            = w;
        pbuf[NBLK + blockIdx.x]     = i2;
        pbuf[2 * NBLK + blockIdx.x] = t2;
    }
}

// ---------------------------------------------------------------------------
// Finalize: reduce 512 partials per quantity (double accum) + scalar.
// ---------------------------------------------------------------------------
__global__ __launch_bounds__(256) void finalize_kernel(const float* __restrict__ pbuf,
                                                       float* __restrict__ out) {
    const int tidx = threadIdx.x;
    double w = 0.0, i2 = 0.0, t2 = 0.0;
    for (int k = tidx; k < NBLK; k += 256) {
        w  += (double)pbuf[k];
        i2 += (double)pbuf[NBLK + k];
        t2 += (double)pbuf[2 * NBLK + k];
    }
#pragma unroll
    for (int off = 32; off > 0; off >>= 1) {
        w  += __shfl_down(w,  off, 64);
        i2 += __shfl_down(i2, off, 64);
        t2 += __shfl_down(t2, off, 64);
    }
    __shared__ double red[3][4];
    const int wave = tidx >> 6;
    if ((tidx & 63) == 0) { red[0][wave] = w; red[1][wave] = i2; red[2][wave] = t2; }
    __syncthreads();
    if (tidx == 0) {
        double ws = 0.0, is = 0.0, ts = 0.0;
        for (int k = 0; k < 4; ++k) { ws += red[0][k]; is += red[1][k]; ts += red[2][k]; }
        const double wbce   = ws / (double)NTOT;
        const double union_ = ts - is;
        const double wiou   = 1.0 - (is + 1.0) / (union_ + 1.0);
        out[0] = (float)(wbce + wiou);
    }
}

extern "C" void kernel_launch(void* const* d_in, const int* in_sizes, int n_in,
                              void* d_out, int out_size, void* d_ws, size_t ws_size,
                              hipStream_t stream) {
    const float* logits = (const float*)d_in[0];
    const float* targ   = (const float*)d_in[1];
    float* out          = (float*)d_out;
    float* pbuf         = (float*)d_ws;     // 3*NBLK floats (6 KB)

    mega_kernel<<<NBLK, 1024, 0, stream>>>(logits, targ, pbuf);
    finalize_kernel<<<1, 256, 0, stream>>>(pbuf, out);
}

// Round 11
// 148.100 us; speedup vs baseline: 1.1289x; 1.0083x over previous
//
#include <hip/hip_runtime.h>
#include <math.h>

#define BATCH 64
#define HH 512
#define WW 512
#define KRAD 15
#define KSZ 31
#define NTOT ((size_t)BATCH * HH * WW)
#define TILE_Y 64
#define NCHUNK (HH / TILE_Y)            // 8
#define NBLK (BATCH * NCHUNK)           // 512 blocks
#define RING 64                         // fp16 prefix ring rows (64 KB, &63 free)

typedef _Float16 h8 __attribute__((ext_vector_type(8)));

// Wave64 inclusive add-scan via DPP (LLVM AMDGPUAtomicOptimizer sequence).
// Pure VALU: zero LDS-pipe traffic.
__device__ __forceinline__ float dpp_scan_add(float v) {
    int t;
    t = __builtin_amdgcn_update_dpp(0, __float_as_int(v), 0x111, 0xf, 0xf, false); // row_shr:1
    v += __int_as_float(t);
    t = __builtin_amdgcn_update_dpp(0, __float_as_int(v), 0x112, 0xf, 0xf, false); // row_shr:2
    v += __int_as_float(t);
    t = __builtin_amdgcn_update_dpp(0, __float_as_int(v), 0x114, 0xf, 0xf, false); // row_shr:4
    v += __int_as_float(t);
    t = __builtin_amdgcn_update_dpp(0, __float_as_int(v), 0x118, 0xf, 0xf, false); // row_shr:8
    v += __int_as_float(t);
    t = __builtin_amdgcn_update_dpp(0, __float_as_int(v), 0x142, 0xa, 0xf, false); // row_bcast:15 -> rows 1,3
    v += __int_as_float(t);
    t = __builtin_amdgcn_update_dpp(0, __float_as_int(v), 0x143, 0xc, 0xf, false); // row_bcast:31 -> rows 2,3
    v += __int_as_float(t);
    return v;
}

// ---------------------------------------------------------------------------
// TILE_Y=64, 64-row fp16 PREFIX ring, two whole-block phases:
//   scan rel 0..61 -> B -> compute rows 0..31 -> B -> scan rel 62..93
//   (slots 62,63,0..29; live 30..61 untouched) -> B -> compute rows 32..63.
// Scan stores the horizontal PREFIX P (not the windowed H): no window
// shuffles, no tot broadcast. Stage 2 forms H = P[min(x+15,511)] - P[x-16]
// with clamped static indices (2 extra conflict-free ds_read_u16/elem).
// ---------------------------------------------------------------------------
__global__ __launch_bounds__(1024, 8) void mega_kernel(const float* __restrict__ logits,
                                                       const float* __restrict__ targ,
                                                       float* __restrict__ pbuf) {
    __shared__ _Float16 Pring[RING * WW];   // 64 KB
    __shared__ float red[3][16];

    const int b     = blockIdx.x >> 3;          // batch
    const int chunk = blockIdx.x & (NCHUNK - 1);
    const int y0    = chunk * TILE_Y;

    const int wave = threadIdx.x >> 6;          // 0..15
    const int lane = threadIdx.x & 63;

    // Scan one row (rel = y_abs-(y0-15)): store fp16 PREFIX into slot rel&63.
    // Zero-writes out-of-range rows (zero-pad semantics).
    auto scan_row = [&](int rel) {
        const int y_abs = y0 - KRAD + rel;
        h8 hv = {};
        if (y_abs >= 0 && y_abs < HH) {
            const float4* rp = (const float4*)(targ + ((size_t)b * HH + y_abs) * WW);
            float4 a  = rp[2 * lane];
            float4 b4 = rp[2 * lane + 1];
            float v[8] = {a.x, a.y, a.z, a.w, b4.x, b4.y, b4.z, b4.w};

            float T = 0.0f;
            float P[8];
#pragma unroll
            for (int j = 0; j < 8; ++j) { T += v[j]; P[j] = T; }

            const float incl = dpp_scan_add(T);
            const float excl = incl - T;
#pragma unroll
            for (int j = 0; j < 8; ++j) hv[j] = (_Float16)(P[j] + excl);
        }
        *(h8*)&Pring[(rel & (RING - 1)) * WW + lane * 8] = hv;
    };

    // ---- Phase A scan: rel 0..61 (slots 0..61) ----
#pragma unroll
    for (int i = 0; i < 4; ++i) {
        const int rel = wave + 16 * i;
        if (rel < 62) scan_row(rel);
    }
    __syncthreads();

    // ---- Compute setup (threads 0..511, one column each) ----
    const int x = threadIdx.x;
    const float* Tp = targ   + ((size_t)b * HH + y0) * WW + x;
    const float* Lp = logits + ((size_t)b * HH + y0) * WW + x;
    const float inv_ksq = 1.0f / (float)(KSZ * KSZ);
    float a_wbce = 0.0f, a_int = 0.0f, a_tot = 0.0f;

    const int  xa     = (x + KRAD > WW - 1) ? (WW - 1) : (x + KRAD);
    const int  xbc    = (x - KRAD - 1 < 0) ? 0 : (x - KRAD - 1);
    const bool has_lo = (x >= KRAD + 1);

    // H(rel, x) from the prefix ring (2 conflict-free u16 reads)
    auto Hval = [&](int rel) -> float {
        const _Float16* row = &Pring[(rel & (RING - 1)) * WW];
        const float hi = (float)row[xa];
        float lo = (float)row[xbc];
        lo = has_lo ? lo : 0.0f;
        return hi - lo;
    };

    float vsum = 0.0f;
    if (x < WW) {
        // window for row 0: rel 0..30 (invalid rows zero-filled)
#pragma unroll
        for (int r = 0; r <= 30; ++r) vsum += Hval(r);
    }

    auto compute32 = [&](int ylo) {
        if (x < WW) {
#pragma unroll 4
            for (int j = 0; j < 32; ++j) {
                const int y = ylo + j;
                if (y > 0)
                    vsum += Hval(y + 30) - Hval(y - 1);

                const float s = vsum * inv_ksq;
                const float t = Tp[(size_t)y * WW];
                const float L = __builtin_nontemporal_load(Lp + (size_t)y * WW);

                const float weit = 1.0f + 5.0f * fabsf(s - t);
                const float e  = __expf(-fabsf(L));
                const float r  = __builtin_amdgcn_rcpf(1.0f + e);
                const float lg = __logf(1.0f + e);          // softplus(-|L|)
                const float sp  = fmaxf(L, 0.0f) + lg;      // softplus(L)
                const float bce = sp - t * L;
                const float p   = (L >= 0.0f) ? r : e * r;  // sigmoid(L)

                a_wbce += weit * bce;
                a_int  += p * t * weit;
                a_tot  += (p + t) * weit;
            }
        }
    };

    // ---- Phase A compute: rows 0..31 (reads slots 0..61 only) ----
    compute32(0);
    __syncthreads();

    // ---- Phase B scan: rel 62..93 -> slots 62,63,0..29 (live 30..61 kept) ----
    scan_row(62 + wave);
    scan_row(78 + wave);
    __syncthreads();

    // ---- Phase B compute: rows 32..63 ----
    compute32(32);

    // ---- Block reduction ----
#pragma unroll
    for (int off = 32; off > 0; off >>= 1) {
        a_wbce += __shfl_down(a_wbce, off, 64);
        a_int  += __shfl_down(a_int,  off, 64);
        a_tot  += __shfl_down(a_tot,  off, 64);
    }

    if (lane == 0) {
        red[0][wave] = a_wbce; red[1][wave] = a_int; red[2][wave] = a_tot;
    }
    __syncthreads();
    if (threadIdx.x == 0) {
        float w = 0.0f, i2 = 0.0f, t2 = 0.0f;
#pragma unroll
        for (int k = 0; k < 16; ++k) { w += red[0][k]; i2 += red[1][k]; t2 += red[2][k]; }
        pbuf[blockIdx.x]            = w;
        pbuf[NBLK + blockIdx.x]     = i2;
        pbuf[2 * NBLK + blockIdx.x] = t2;
    }
}

// ---------------------------------------------------------------------------
// Finalize: reduce 512 partials per quantity (double accum) + scalar.
// ---------------------------------------------------------------------------
__global__ __launch_bounds__(256) void finalize_kernel(const float* __restrict__ pbuf,
                                                       float* __restrict__ out) {
    const int tidx = threadIdx.x;
    double w = 0.0, i2 = 0.0, t2 = 0.0;
    for (int k = tidx; k < NBLK; k += 256) {
        w  += (double)pbuf[k];
        i2 += (double)pbuf[NBLK + k];
        t2 += (double)pbuf[2 * NBLK + k];
    }
#pragma unroll
    for (int off = 32; off > 0; off >>= 1) {
        w  += __shfl_down(w,  off, 64);
        i2 += __shfl_down(i2, off, 64);
        t2 += __shfl_down(t2, off, 64);
    }
    __shared__ double red[3][4];
    const int wave = tidx >> 6;
    if ((tidx & 63) == 0) { red[0][wave] = w; red[1][wave] = i2; red[2][wave] = t2; }
    __syncthreads();
    if (tidx == 0) {
        double ws = 0.0, is = 0.0, ts = 0.0;
        for (int k = 0; k < 4; ++k) { ws += red[0][k]; is += red[1][k]; ts += red[2][k]; }
        const double wbce   = ws / (double)NTOT;
        const double union_ = ts - is;
        const double wiou   = 1.0 - (is + 1.0) / (union_ + 1.0);
        out[0] = (float)(wbce + wiou);
    }
}

extern "C" void kernel_launch(void* const* d_in, const int* in_sizes, int n_in,
                              void* d_out, int out_size, void* d_ws, size_t ws_size,
                              hipStream_t stream) {
    const float* logits = (const float*)d_in[0];
    const float* targ   = (const float*)d_in[1];
    float* out          = (float*)d_out;
    float* pbuf         = (float*)d_ws;     // 3*NBLK floats (6 KB)

    mega_kernel<<<NBLK, 1024, 0, stream>>>(logits, targ, pbuf);
    finalize_kernel<<<1, 256, 0, stream>>>(pbuf, out);
}